// Round 5
// baseline (1060.406 us; speedup 1.0000x reference)
//
#include <hip/hip_runtime.h>

#define NL 8
#define NM 8192
#define ND 16
#define NH 256
#define NF 64
#define NN (NL * NM)

__device__ __forceinline__ float lrelu(float x) { return fmaxf(x, 0.1f * x); }

// ---------- precompute attention constants: cst[32..63] = W_p2 @ av_p ----------
__global__ void precomp_kernel(const float* __restrict__ W_p2, const float* __restrict__ av,
                               float* __restrict__ cst)
{
    int j = threadIdx.x;   // 32 threads
    float w = 0.f;
    for (int k = 0; k < 32; ++k) w += W_p2[j * 32 + k] * av[32 + k];
    cst[32 + j] = w;
}

// ---------- Level 0: h = mlp_pi(delay) + g epilogue ----------
__global__ __launch_bounds__(512) void level0_kernel(
    const float* __restrict__ delay,
    const float* __restrict__ W1, const float* __restrict__ b1,
    const float* __restrict__ W2, const float* __restrict__ b2,
    const float* __restrict__ av,
    float* __restrict__ h_all, float* __restrict__ g_all)
{
    const int tid = threadIdx.x;
    const int row0 = blockIdx.x * 32;
    __shared__ __align__(16) float sH[32][128];

    for (int x = tid; x < 32 * 128; x += 512) {
        int r = x >> 7, j = x & 127;
        sH[r][j] = lrelu(delay[row0 + r] * W1[j] + b1[j]);
    }
    __syncthreads();

    const int tj = tid & 63, tr = tid >> 6;
    const float4 av4 = *(const float4*)(av + 64 + tj * 4);
    float acc[4][4];
    #pragma unroll
    for (int a = 0; a < 4; ++a)
        #pragma unroll
        for (int b = 0; b < 4; ++b) acc[a][b] = 0.f;

    for (int k = 0; k < 128; k += 4) {
        float4 w0 = *(const float4*)(W2 + (size_t)(k + 0) * 256 + tj * 4);
        float4 w1 = *(const float4*)(W2 + (size_t)(k + 1) * 256 + tj * 4);
        float4 w2 = *(const float4*)(W2 + (size_t)(k + 2) * 256 + tj * 4);
        float4 w3 = *(const float4*)(W2 + (size_t)(k + 3) * 256 + tj * 4);
        #pragma unroll
        for (int rr = 0; rr < 4; ++rr) {
            float4 xv = *(const float4*)(&sH[tr * 4 + rr][k]);
            acc[rr][0] += xv.x * w0.x + xv.y * w1.x + xv.z * w2.x + xv.w * w3.x;
            acc[rr][1] += xv.x * w0.y + xv.y * w1.y + xv.z * w2.y + xv.w * w3.y;
            acc[rr][2] += xv.x * w0.z + xv.y * w1.z + xv.z * w2.z + xv.w * w3.z;
            acc[rr][3] += xv.x * w0.w + xv.y * w1.w + xv.z * w2.w + xv.w * w3.w;
        }
    }
    float4 bv = *(const float4*)(b2 + tj * 4);
    #pragma unroll
    for (int rr = 0; rr < 4; ++rr) {
        const int row = row0 + tr * 4 + rr;
        float4 o;
        o.x = acc[rr][0] + bv.x; o.y = acc[rr][1] + bv.y;
        o.z = acc[rr][2] + bv.z; o.w = acc[rr][3] + bv.w;
        *(float4*)(h_all + (size_t)row * NH + tj * 4) = o;
        float gp = o.x * av4.x + o.y * av4.y + o.z * av4.z + o.w * av4.w;
        #pragma unroll
        for (int off = 1; off < 64; off <<= 1) gp += __shfl_xor(gp, off);
        if (tj == 0) g_all[row] = gp;
    }
}

// ---------- Fused per-level: streamed attention -> LDS -> mlp_n ----------
// 256 thr (4 waves), 8 rows/block, 1024 blocks. Wave w: rows w*2, w*2+1.
__global__ __launch_bounds__(256) void level_kernel(
    const float* __restrict__ h_all, const float* __restrict__ g_all,
    const float* __restrict__ bit_pos, const int* __restrict__ nbr_idx,
    const float* __restrict__ W_p1, const float* __restrict__ b_p1,
    const float* __restrict__ cst,
    const float* __restrict__ W1, const float* __restrict__ b1,
    const float* __restrict__ W2, const float* __restrict__ b2,
    const int* __restrict__ is_po, const float* __restrict__ av,
    float* __restrict__ h_out, float* __restrict__ g_all_out, int level)
{
    const int tid = threadIdx.x;
    const int w = tid >> 6, lane = tid & 63;
    const int row0 = blockIdx.x * 8;
    __shared__ __align__(16) float sX[8][NH];
    __shared__ __align__(16) float sH[8][128];

    // ---- Phase A: attention for rows w*2 .. w*2+1 ----
    #pragma unroll
    for (int mi = 0; mi < 2; ++mi) {
        const int mrow = w * 2 + mi;
        const int m = row0 + mrow;
        const int d = lane & 15, jj = lane >> 4;
        const size_t ebase = ((size_t)(level - 1) * NM + m) * ND;

        const int   idx = nbr_idx[ebase + d];
        const float bp  = bit_pos[ebase + d];

        // collapsed mlp_p: 4 jj-groups each cover 8 of 32 hidden units
        float ep = 0.f;
        #pragma unroll
        for (int t = 0; t < 8; ++t) {
            int j = jj * 8 + t;
            ep += cst[32 + j] * lrelu(bp * W_p1[j] + b_p1[j]);
        }
        ep += __shfl_xor(ep, 16);
        ep += __shfl_xor(ep, 32);

        // e = e_h + e_p (e_t constant over d -> cancels in softmax)
        float e = g_all[idx] + ep;
        float mx = e;
        #pragma unroll
        for (int off = 1; off < 16; off <<= 1) mx = fmaxf(mx, __shfl_xor(mx, off));
        float wexp = __expf(e - mx);
        float s = wexp;
        #pragma unroll
        for (int off = 1; off < 16; off <<= 1) s += __shfl_xor(s, off);
        const float alpha = wexp / s;

        // streamed weighted sum: 16 independent row loads, lane owns 4 cols
        float4 acc = make_float4(0.f, 0.f, 0.f, 0.f);
        #pragma unroll
        for (int d2 = 0; d2 < 16; ++d2) {
            float a = __shfl(alpha, d2);
            int   r = __shfl(idx, d2);
            float4 v = *(const float4*)(h_all + (size_t)r * NH + lane * 4);
            acc.x += a * v.x; acc.y += a * v.y; acc.z += a * v.z; acc.w += a * v.w;
        }
        *(float4*)(&sX[mrow][lane * 4]) = acc;
    }
    __syncthreads();

    // ---- Phase B layer 1: (8x256)@(256x128), lrelu ----
    {
        const int tj = tid & 31, tr = tid >> 5;   // 32 col-thr x 4 cols; row = tr
        float acc[4] = {0.f, 0.f, 0.f, 0.f};

        for (int k = 0; k < NH; k += 4) {
            float4 w0 = *(const float4*)(W1 + (size_t)(k + 0) * 128 + tj * 4);
            float4 w1 = *(const float4*)(W1 + (size_t)(k + 1) * 128 + tj * 4);
            float4 w2 = *(const float4*)(W1 + (size_t)(k + 2) * 128 + tj * 4);
            float4 w3 = *(const float4*)(W1 + (size_t)(k + 3) * 128 + tj * 4);
            float4 xv = *(const float4*)(&sX[tr][k]);
            acc[0] += xv.x * w0.x + xv.y * w1.x + xv.z * w2.x + xv.w * w3.x;
            acc[1] += xv.x * w0.y + xv.y * w1.y + xv.z * w2.y + xv.w * w3.y;
            acc[2] += xv.x * w0.z + xv.y * w1.z + xv.z * w2.z + xv.w * w3.z;
            acc[3] += xv.x * w0.w + xv.y * w1.w + xv.z * w2.w + xv.w * w3.w;
        }
        float4 bv = *(const float4*)(b1 + tj * 4);
        float4 o;
        o.x = lrelu(acc[0] + bv.x); o.y = lrelu(acc[1] + bv.y);
        o.z = lrelu(acc[2] + bv.z); o.w = lrelu(acc[3] + bv.w);
        *(float4*)(&sH[tr][tj * 4]) = o;
    }
    __syncthreads();

    // ---- Phase B layer 2: (8x128)@(128x256), cond-relu, store + g epilogue ----
    {
        const int tj = tid & 63, tr = tid >> 6;   // wave tr owns rows tr*2..tr*2+1
        const float4 av4 = *(const float4*)(av + 64 + tj * 4);
        float acc[2][4];
        #pragma unroll
        for (int a = 0; a < 2; ++a)
            #pragma unroll
            for (int b = 0; b < 4; ++b) acc[a][b] = 0.f;

        for (int k = 0; k < 128; k += 4) {
            float4 w0 = *(const float4*)(W2 + (size_t)(k + 0) * 256 + tj * 4);
            float4 w1 = *(const float4*)(W2 + (size_t)(k + 1) * 256 + tj * 4);
            float4 w2 = *(const float4*)(W2 + (size_t)(k + 2) * 256 + tj * 4);
            float4 w3 = *(const float4*)(W2 + (size_t)(k + 3) * 256 + tj * 4);
            #pragma unroll
            for (int rr = 0; rr < 2; ++rr) {
                float4 xv = *(const float4*)(&sH[tr * 2 + rr][k]);
                acc[rr][0] += xv.x * w0.x + xv.y * w1.x + xv.z * w2.x + xv.w * w3.x;
                acc[rr][1] += xv.x * w0.y + xv.y * w1.y + xv.z * w2.y + xv.w * w3.y;
                acc[rr][2] += xv.x * w0.z + xv.y * w1.z + xv.z * w2.z + xv.w * w3.z;
                acc[rr][3] += xv.x * w0.w + xv.y * w1.w + xv.z * w2.w + xv.w * w3.w;
            }
        }
        float4 bv = *(const float4*)(b2 + tj * 4);
        #pragma unroll
        for (int rr = 0; rr < 2; ++rr) {
            const int gm = level * NM + row0 + tr * 2 + rr;
            bool po = (is_po[gm] == 1);
            float4 o;
            o.x = acc[rr][0] + bv.x; o.y = acc[rr][1] + bv.y;
            o.z = acc[rr][2] + bv.z; o.w = acc[rr][3] + bv.w;
            if (!po) {
                o.x = fmaxf(o.x, 0.f); o.y = fmaxf(o.y, 0.f);
                o.z = fmaxf(o.z, 0.f); o.w = fmaxf(o.w, 0.f);
            }
            *(float4*)(h_out + (size_t)gm * NH + tj * 4) = o;
            float gp = o.x * av4.x + o.y * av4.y + o.z * av4.z + o.w * av4.w;
            #pragma unroll
            for (int off = 1; off < 64; off <<= 1) gp += __shfl_xor(gp, off);
            if (tj == 0) g_all_out[gm] = gp;
        }
    }
}

// ---------- Final readout: 512 thr (8 waves) / 16 rows / 512 blocks ----------
__global__ __launch_bounds__(512) void final_kernel(
    const float* __restrict__ h_gnn, const float* __restrict__ po_feat,
    const float* __restrict__ Wg1, const float* __restrict__ bg1,
    const float* __restrict__ Wg2, const float* __restrict__ bg2,
    const float* __restrict__ Wo1, const float* __restrict__ bo1,
    const float* __restrict__ Wo2, const float* __restrict__ bo2,
    float* __restrict__ out)
{
    const int tid = threadIdx.x;
    const int row0 = blockIdx.x * 16;
    __shared__ __align__(16) float sx[16][512];
    __shared__ __align__(16) float sg[16][128];

    for (int x = tid; x < 16 * 64; x += 512) {
        int r = x >> 6, c = x & 63;
        *(float4*)(&sx[r][c * 4]) = *(const float4*)(h_gnn + (size_t)(row0 + r) * NH + c * 4);
    }
    for (int x = tid; x < 16 * 128; x += 512) {
        int r = x >> 7, j = x & 127;
        sg[r][j] = lrelu(po_feat[row0 + r] * Wg1[j] + bg1[j]);
    }
    __syncthreads();

    // h_global = sg @ Wg2 + bg2 -> sx[:, 256:]; wave tr owns rows tr*2..tr*2+1
    {
        const int tj = tid & 63, tr = tid >> 6;
        float acc[2][4];
        #pragma unroll
        for (int a = 0; a < 2; ++a)
            #pragma unroll
            for (int b = 0; b < 4; ++b) acc[a][b] = 0.f;

        for (int k = 0; k < 128; k += 4) {
            float4 w0 = *(const float4*)(Wg2 + (size_t)(k + 0) * 256 + tj * 4);
            float4 w1 = *(const float4*)(Wg2 + (size_t)(k + 1) * 256 + tj * 4);
            float4 w2 = *(const float4*)(Wg2 + (size_t)(k + 2) * 256 + tj * 4);
            float4 w3 = *(const float4*)(Wg2 + (size_t)(k + 3) * 256 + tj * 4);
            #pragma unroll
            for (int rr = 0; rr < 2; ++rr) {
                float4 xv = *(const float4*)(&sg[tr * 2 + rr][k]);
                acc[rr][0] += xv.x * w0.x + xv.y * w1.x + xv.z * w2.x + xv.w * w3.x;
                acc[rr][1] += xv.x * w0.y + xv.y * w1.y + xv.z * w2.y + xv.w * w3.y;
                acc[rr][2] += xv.x * w0.z + xv.y * w1.z + xv.z * w2.z + xv.w * w3.z;
                acc[rr][3] += xv.x * w0.w + xv.y * w1.w + xv.z * w2.w + xv.w * w3.w;
            }
        }
        float4 bv = *(const float4*)(bg2 + tj * 4);
        #pragma unroll
        for (int rr = 0; rr < 2; ++rr) {
            float4 o;
            o.x = acc[rr][0] + bv.x; o.y = acc[rr][1] + bv.y;
            o.z = acc[rr][2] + bv.z; o.w = acc[rr][3] + bv.w;
            *(float4*)(&sx[tr * 2 + rr][256 + tj * 4]) = o;
        }
    }
    __syncthreads();

    // o1 = lrelu(sx @ Wo1 + bo1) fused with out = o1 @ Wo2 + bo2
    {
        const int tj = tid & 63, tr = tid >> 6;
        float acc[2][4];
        #pragma unroll
        for (int a = 0; a < 2; ++a)
            #pragma unroll
            for (int b = 0; b < 4; ++b) acc[a][b] = 0.f;

        for (int k = 0; k < 512; k += 4) {
            float4 w0 = *(const float4*)(Wo1 + (size_t)(k + 0) * 256 + tj * 4);
            float4 w1 = *(const float4*)(Wo1 + (size_t)(k + 1) * 256 + tj * 4);
            float4 w2 = *(const float4*)(Wo1 + (size_t)(k + 2) * 256 + tj * 4);
            float4 w3 = *(const float4*)(Wo1 + (size_t)(k + 3) * 256 + tj * 4);
            #pragma unroll
            for (int rr = 0; rr < 2; ++rr) {
                float4 xv = *(const float4*)(&sx[tr * 2 + rr][k]);
                acc[rr][0] += xv.x * w0.x + xv.y * w1.x + xv.z * w2.x + xv.w * w3.x;
                acc[rr][1] += xv.x * w0.y + xv.y * w1.y + xv.z * w2.y + xv.w * w3.y;
                acc[rr][2] += xv.x * w0.z + xv.y * w1.z + xv.z * w2.z + xv.w * w3.z;
                acc[rr][3] += xv.x * w0.w + xv.y * w1.w + xv.z * w2.w + xv.w * w3.w;
            }
        }
        float4 bv = *(const float4*)(bo1 + tj * 4);
        float4 wv = *(const float4*)(Wo2 + tj * 4);
        #pragma unroll
        for (int rr = 0; rr < 2; ++rr) {
            float c = lrelu(acc[rr][0] + bv.x) * wv.x
                    + lrelu(acc[rr][1] + bv.y) * wv.y
                    + lrelu(acc[rr][2] + bv.z) * wv.z
                    + lrelu(acc[rr][3] + bv.w) * wv.w;
            #pragma unroll
            for (int off = 1; off < 64; off <<= 1) c += __shfl_xor(c, off);
            if (tj == 0) out[row0 + tr * 2 + rr] = c + bo2[0];
        }
    }
}

extern "C" void kernel_launch(void* const* d_in, const int* in_sizes, int n_in,
                              void* d_out, int out_size, void* d_ws, size_t ws_size,
                              hipStream_t stream) {
    const float* W_pi1 = (const float*)d_in[0];
    const float* b_pi1 = (const float*)d_in[1];
    const float* W_pi2 = (const float*)d_in[2];
    const float* b_pi2 = (const float*)d_in[3];
    const float* W_p1  = (const float*)d_in[8];
    const float* b_p1  = (const float*)d_in[9];
    const float* W_p2  = (const float*)d_in[10];
    const float* W_n1  = (const float*)d_in[12];
    const float* b_n1  = (const float*)d_in[13];
    const float* W_n2  = (const float*)d_in[14];
    const float* b_n2  = (const float*)d_in[15];
    const float* W_g1  = (const float*)d_in[16];
    const float* b_g1  = (const float*)d_in[17];
    const float* W_g2  = (const float*)d_in[18];
    const float* b_g2  = (const float*)d_in[19];
    const float* W_o1  = (const float*)d_in[20];
    const float* b_o1  = (const float*)d_in[21];
    const float* W_o2  = (const float*)d_in[22];
    const float* b_o2  = (const float*)d_in[23];
    const float* av    = (const float*)d_in[24];
    const float* delay = (const float*)d_in[26];
    const float* bit_pos = (const float*)d_in[27];
    const float* po_feat = (const float*)d_in[28];
    const int*   is_po   = (const int*)d_in[29];
    const int*   nbr_idx = (const int*)d_in[30];

    float* h_all = (float*)d_ws;                       // NN*NH floats
    float* g_all = h_all + (size_t)NN * NH;            // NN floats
    float* cst   = g_all + NN;                         // 64 floats
    float* out   = (float*)d_out;

    precomp_kernel<<<1, 32, 0, stream>>>(W_p2, av, cst);

    level0_kernel<<<NM / 32, 512, 0, stream>>>(delay, W_pi1, b_pi1, W_pi2, b_pi2,
                                               av, h_all, g_all);

    for (int level = 1; level < NL; ++level) {
        level_kernel<<<NM / 8, 256, 0, stream>>>(h_all, g_all, bit_pos, nbr_idx,
                                                 W_p1, b_p1, cst,
                                                 W_n1, b_n1, W_n2, b_n2,
                                                 is_po, av, h_all, g_all, level);
    }

    final_kernel<<<NM / 16, 512, 0, stream>>>(h_all + (size_t)(NN - NM) * NH, po_feat,
                                              W_g1, b_g1, W_g2, b_g2,
                                              W_o1, b_o1, W_o2, b_o2, out);
}

// Round 6
// 393.528 us; speedup vs baseline: 2.6946x; 2.6946x over previous
//
#include <hip/hip_runtime.h>

#define NL 8
#define NM 8192
#define ND 16
#define NH 256
#define NF 64
#define NN (NL * NM)

typedef unsigned short u16;

__device__ __forceinline__ float lrelu(float x) { return fmaxf(x, 0.1f * x); }

// f32 -> bf16 round-to-nearest-even
__device__ __forceinline__ u16 f2bf(float x) {
    union { float f; unsigned int u; } v; v.f = x;
    unsigned int r = (v.u + 0x7FFFu + ((v.u >> 16) & 1u)) >> 16;
    return (u16)r;
}
__device__ __forceinline__ ushort4 f4_to_bf4(float4 o) {
    ushort4 r; r.x = f2bf(o.x); r.y = f2bf(o.y); r.z = f2bf(o.z); r.w = f2bf(o.w);
    return r;
}
__device__ __forceinline__ float bf2f(u16 u) {
    union { unsigned int u; float f; } v; v.u = ((unsigned int)u) << 16;
    return v.f;
}
__device__ __forceinline__ float4 bf4_to_f4(ushort4 h) {
    return make_float4(bf2f(h.x), bf2f(h.y), bf2f(h.z), bf2f(h.w));
}

// ---------- precompute attention constants: cst[32..63] = W_p2 @ av_p ----------
__global__ void precomp_kernel(const float* __restrict__ W_p2, const float* __restrict__ av,
                               float* __restrict__ cst)
{
    int j = threadIdx.x;   // 32 threads
    float w = 0.f;
    for (int k = 0; k < 32; ++k) w += W_p2[j * 32 + k] * av[32 + k];
    cst[32 + j] = w;
}

// ---------- Level 0: h = mlp_pi(delay) (bf16 store) + g epilogue ----------
__global__ __launch_bounds__(512) void level0_kernel(
    const float* __restrict__ delay,
    const float* __restrict__ W1, const float* __restrict__ b1,
    const float* __restrict__ W2, const float* __restrict__ b2,
    const float* __restrict__ av,
    u16* __restrict__ h_all, float* __restrict__ g_all)
{
    const int tid = threadIdx.x;
    const int row0 = blockIdx.x * 32;
    __shared__ __align__(16) float sH[32][128];

    for (int x = tid; x < 32 * 128; x += 512) {
        int r = x >> 7, j = x & 127;
        sH[r][j] = lrelu(delay[row0 + r] * W1[j] + b1[j]);
    }
    __syncthreads();

    const int tj = tid & 63, tr = tid >> 6;
    const float4 av4 = *(const float4*)(av + 64 + tj * 4);
    float acc[4][4];
    #pragma unroll
    for (int a = 0; a < 4; ++a)
        #pragma unroll
        for (int b = 0; b < 4; ++b) acc[a][b] = 0.f;

    for (int k = 0; k < 128; k += 4) {
        float4 w0 = *(const float4*)(W2 + (size_t)(k + 0) * 256 + tj * 4);
        float4 w1 = *(const float4*)(W2 + (size_t)(k + 1) * 256 + tj * 4);
        float4 w2 = *(const float4*)(W2 + (size_t)(k + 2) * 256 + tj * 4);
        float4 w3 = *(const float4*)(W2 + (size_t)(k + 3) * 256 + tj * 4);
        #pragma unroll
        for (int rr = 0; rr < 4; ++rr) {
            float4 xv = *(const float4*)(&sH[tr * 4 + rr][k]);
            acc[rr][0] += xv.x * w0.x + xv.y * w1.x + xv.z * w2.x + xv.w * w3.x;
            acc[rr][1] += xv.x * w0.y + xv.y * w1.y + xv.z * w2.y + xv.w * w3.y;
            acc[rr][2] += xv.x * w0.z + xv.y * w1.z + xv.z * w2.z + xv.w * w3.z;
            acc[rr][3] += xv.x * w0.w + xv.y * w1.w + xv.z * w2.w + xv.w * w3.w;
        }
    }
    float4 bv = *(const float4*)(b2 + tj * 4);
    #pragma unroll
    for (int rr = 0; rr < 4; ++rr) {
        const int row = row0 + tr * 4 + rr;
        float4 o;
        o.x = acc[rr][0] + bv.x; o.y = acc[rr][1] + bv.y;
        o.z = acc[rr][2] + bv.z; o.w = acc[rr][3] + bv.w;
        *(ushort4*)(h_all + (size_t)row * NH + tj * 4) = f4_to_bf4(o);
        float gp = o.x * av4.x + o.y * av4.y + o.z * av4.z + o.w * av4.w;
        #pragma unroll
        for (int off = 1; off < 64; off <<= 1) gp += __shfl_xor(gp, off);
        if (tj == 0) g_all[row] = gp;
    }
}

// ---------- Attention per level: 1 wave per m; g-gather alpha + single bf16 streamed pass ----------
__global__ __launch_bounds__(256) void attn_kernel(
    const u16* __restrict__ h_all, const float* __restrict__ g_all,
    const float* __restrict__ bit_pos, const int* __restrict__ nbr_idx,
    const float* __restrict__ W_p1, const float* __restrict__ b_p1,
    const float* __restrict__ cst,
    float* __restrict__ neigh, int level)
{
    const int w = threadIdx.x >> 6, lane = threadIdx.x & 63;
    const int m = blockIdx.x * 4 + w;
    const int d = lane & 15, jj = lane >> 4;
    const size_t ebase = ((size_t)(level - 1) * NM + m) * ND;

    const int   idx = nbr_idx[ebase + d];
    const float bp  = bit_pos[ebase + d];

    // collapsed mlp_p: 4 jj-groups each cover 8 of the 32 hidden units
    float ep = 0.f;
    #pragma unroll
    for (int t = 0; t < 8; ++t) {
        int j = jj * 8 + t;
        ep += cst[32 + j] * lrelu(bp * W_p1[j] + b_p1[j]);
    }
    ep += __shfl_xor(ep, 16);
    ep += __shfl_xor(ep, 32);

    // e = e_h + e_p  (e_t is constant over d -> cancels in softmax)
    float e = g_all[idx] + ep;
    float mx = e;
    #pragma unroll
    for (int off = 1; off < 16; off <<= 1) mx = fmaxf(mx, __shfl_xor(mx, off));
    float wexp = __expf(e - mx);
    float s = wexp;
    #pragma unroll
    for (int off = 1; off < 16; off <<= 1) s += __shfl_xor(s, off);
    const float alpha = wexp / s;

    // single streamed weighted sum: 16 independent 512B bf16 row loads
    float4 acc = make_float4(0.f, 0.f, 0.f, 0.f);
    #pragma unroll
    for (int d2 = 0; d2 < 16; ++d2) {
        float a = __shfl(alpha, d2);
        int   r = __shfl(idx, d2);
        ushort4 hv = *(const ushort4*)(h_all + (size_t)r * NH + lane * 4);
        float4 v = bf4_to_f4(hv);
        acc.x += a * v.x; acc.y += a * v.y; acc.z += a * v.z; acc.w += a * v.w;
    }
    *(float4*)(neigh + (size_t)m * NH + lane * 4) = acc;
}

// ---------- Neighborhood MLP: 256 thr / 16 rows / 512 blocks; bf16 h store + g epilogue ----------
__global__ __launch_bounds__(256) void mlp_n_kernel(
    const float* __restrict__ neigh,
    const float* __restrict__ W1, const float* __restrict__ b1,
    const float* __restrict__ W2, const float* __restrict__ b2,
    const int* __restrict__ is_po, const float* __restrict__ av,
    u16* __restrict__ h_all, float* __restrict__ g_all, int level)
{
    const int tid = threadIdx.x;
    const int row0 = blockIdx.x * 16;
    __shared__ __align__(16) float sX[16][NH];
    __shared__ __align__(16) float sH[16][128];

    for (int x = tid; x < 16 * 64; x += 256) {
        int r = x >> 6, c = x & 63;
        *(float4*)(&sX[r][c * 4]) = *(const float4*)(neigh + (size_t)(row0 + r) * NH + c * 4);
    }
    __syncthreads();

    // layer 1: (16x256)@(256x128), lrelu
    {
        const int tj = tid & 31, tr = tid >> 5;
        float acc[2][4];
        #pragma unroll
        for (int a = 0; a < 2; ++a)
            #pragma unroll
            for (int b = 0; b < 4; ++b) acc[a][b] = 0.f;

        for (int k = 0; k < NH; k += 4) {
            float4 w0 = *(const float4*)(W1 + (size_t)(k + 0) * 128 + tj * 4);
            float4 w1 = *(const float4*)(W1 + (size_t)(k + 1) * 128 + tj * 4);
            float4 w2 = *(const float4*)(W1 + (size_t)(k + 2) * 128 + tj * 4);
            float4 w3 = *(const float4*)(W1 + (size_t)(k + 3) * 128 + tj * 4);
            #pragma unroll
            for (int rr = 0; rr < 2; ++rr) {
                float4 xv = *(const float4*)(&sX[tr * 2 + rr][k]);
                acc[rr][0] += xv.x * w0.x + xv.y * w1.x + xv.z * w2.x + xv.w * w3.x;
                acc[rr][1] += xv.x * w0.y + xv.y * w1.y + xv.z * w2.y + xv.w * w3.y;
                acc[rr][2] += xv.x * w0.z + xv.y * w1.z + xv.z * w2.z + xv.w * w3.z;
                acc[rr][3] += xv.x * w0.w + xv.y * w1.w + xv.z * w2.w + xv.w * w3.w;
            }
        }
        float4 bv = *(const float4*)(b1 + tj * 4);
        #pragma unroll
        for (int rr = 0; rr < 2; ++rr) {
            float4 o;
            o.x = lrelu(acc[rr][0] + bv.x); o.y = lrelu(acc[rr][1] + bv.y);
            o.z = lrelu(acc[rr][2] + bv.z); o.w = lrelu(acc[rr][3] + bv.w);
            *(float4*)(&sH[tr * 2 + rr][tj * 4]) = o;
        }
    }
    __syncthreads();

    // layer 2: (16x128)@(128x256), cond-relu, bf16 store + g epilogue
    {
        const int tj = tid & 63, tr = tid >> 6;
        const float4 av4 = *(const float4*)(av + 64 + tj * 4);
        float acc[4][4];
        #pragma unroll
        for (int a = 0; a < 4; ++a)
            #pragma unroll
            for (int b = 0; b < 4; ++b) acc[a][b] = 0.f;

        for (int k = 0; k < 128; k += 4) {
            float4 w0 = *(const float4*)(W2 + (size_t)(k + 0) * 256 + tj * 4);
            float4 w1 = *(const float4*)(W2 + (size_t)(k + 1) * 256 + tj * 4);
            float4 w2 = *(const float4*)(W2 + (size_t)(k + 2) * 256 + tj * 4);
            float4 w3 = *(const float4*)(W2 + (size_t)(k + 3) * 256 + tj * 4);
            #pragma unroll
            for (int rr = 0; rr < 4; ++rr) {
                float4 xv = *(const float4*)(&sH[tr * 4 + rr][k]);
                acc[rr][0] += xv.x * w0.x + xv.y * w1.x + xv.z * w2.x + xv.w * w3.x;
                acc[rr][1] += xv.x * w0.y + xv.y * w1.y + xv.z * w2.y + xv.w * w3.y;
                acc[rr][2] += xv.x * w0.z + xv.y * w1.z + xv.z * w2.z + xv.w * w3.z;
                acc[rr][3] += xv.x * w0.w + xv.y * w1.w + xv.z * w2.w + xv.w * w3.w;
            }
        }
        float4 bv = *(const float4*)(b2 + tj * 4);
        #pragma unroll
        for (int rr = 0; rr < 4; ++rr) {
            const int gm = level * NM + row0 + tr * 4 + rr;
            bool po = (is_po[gm] == 1);
            float4 o;
            o.x = acc[rr][0] + bv.x; o.y = acc[rr][1] + bv.y;
            o.z = acc[rr][2] + bv.z; o.w = acc[rr][3] + bv.w;
            if (!po) {
                o.x = fmaxf(o.x, 0.f); o.y = fmaxf(o.y, 0.f);
                o.z = fmaxf(o.z, 0.f); o.w = fmaxf(o.w, 0.f);
            }
            *(ushort4*)(h_all + (size_t)gm * NH + tj * 4) = f4_to_bf4(o);
            float gp = o.x * av4.x + o.y * av4.y + o.z * av4.z + o.w * av4.w;
            #pragma unroll
            for (int off = 1; off < 64; off <<= 1) gp += __shfl_xor(gp, off);
            if (tj == 0) g_all[gm] = gp;
        }
    }
}

// ---------- Final readout: 512 thr (8 waves) / 16 rows / 512 blocks ----------
__global__ __launch_bounds__(512) void final_kernel(
    const u16* __restrict__ h_gnn, const float* __restrict__ po_feat,
    const float* __restrict__ Wg1, const float* __restrict__ bg1,
    const float* __restrict__ Wg2, const float* __restrict__ bg2,
    const float* __restrict__ Wo1, const float* __restrict__ bo1,
    const float* __restrict__ Wo2, const float* __restrict__ bo2,
    float* __restrict__ out)
{
    const int tid = threadIdx.x;
    const int row0 = blockIdx.x * 16;
    __shared__ __align__(16) float sx[16][512];
    __shared__ __align__(16) float sg[16][128];

    for (int x = tid; x < 16 * 64; x += 512) {
        int r = x >> 6, c = x & 63;
        ushort4 hv = *(const ushort4*)(h_gnn + (size_t)(row0 + r) * NH + c * 4);
        *(float4*)(&sx[r][c * 4]) = bf4_to_f4(hv);
    }
    for (int x = tid; x < 16 * 128; x += 512) {
        int r = x >> 7, j = x & 127;
        sg[r][j] = lrelu(po_feat[row0 + r] * Wg1[j] + bg1[j]);
    }
    __syncthreads();

    // h_global = sg @ Wg2 + bg2 -> sx[:, 256:]; wave tr owns rows tr*2..tr*2+1
    {
        const int tj = tid & 63, tr = tid >> 6;
        float acc[2][4];
        #pragma unroll
        for (int a = 0; a < 2; ++a)
            #pragma unroll
            for (int b = 0; b < 4; ++b) acc[a][b] = 0.f;

        for (int k = 0; k < 128; k += 4) {
            float4 w0 = *(const float4*)(Wg2 + (size_t)(k + 0) * 256 + tj * 4);
            float4 w1 = *(const float4*)(Wg2 + (size_t)(k + 1) * 256 + tj * 4);
            float4 w2 = *(const float4*)(Wg2 + (size_t)(k + 2) * 256 + tj * 4);
            float4 w3 = *(const float4*)(Wg2 + (size_t)(k + 3) * 256 + tj * 4);
            #pragma unroll
            for (int rr = 0; rr < 2; ++rr) {
                float4 xv = *(const float4*)(&sg[tr * 2 + rr][k]);
                acc[rr][0] += xv.x * w0.x + xv.y * w1.x + xv.z * w2.x + xv.w * w3.x;
                acc[rr][1] += xv.x * w0.y + xv.y * w1.y + xv.z * w2.y + xv.w * w3.y;
                acc[rr][2] += xv.x * w0.z + xv.y * w1.z + xv.z * w2.z + xv.w * w3.z;
                acc[rr][3] += xv.x * w0.w + xv.y * w1.w + xv.z * w2.w + xv.w * w3.w;
            }
        }
        float4 bv = *(const float4*)(bg2 + tj * 4);
        #pragma unroll
        for (int rr = 0; rr < 2; ++rr) {
            float4 o;
            o.x = acc[rr][0] + bv.x; o.y = acc[rr][1] + bv.y;
            o.z = acc[rr][2] + bv.z; o.w = acc[rr][3] + bv.w;
            *(float4*)(&sx[tr * 2 + rr][256 + tj * 4]) = o;
        }
    }
    __syncthreads();

    // o1 = lrelu(sx @ Wo1 + bo1) fused with out = o1 @ Wo2 + bo2
    {
        const int tj = tid & 63, tr = tid >> 6;
        float acc[2][4];
        #pragma unroll
        for (int a = 0; a < 2; ++a)
            #pragma unroll
            for (int b = 0; b < 4; ++b) acc[a][b] = 0.f;

        for (int k = 0; k < 512; k += 4) {
            float4 w0 = *(const float4*)(Wo1 + (size_t)(k + 0) * 256 + tj * 4);
            float4 w1 = *(const float4*)(Wo1 + (size_t)(k + 1) * 256 + tj * 4);
            float4 w2 = *(const float4*)(Wo1 + (size_t)(k + 2) * 256 + tj * 4);
            float4 w3 = *(const float4*)(Wo1 + (size_t)(k + 3) * 256 + tj * 4);
            #pragma unroll
            for (int rr = 0; rr < 2; ++rr) {
                float4 xv = *(const float4*)(&sx[tr * 2 + rr][k]);
                acc[rr][0] += xv.x * w0.x + xv.y * w1.x + xv.z * w2.x + xv.w * w3.x;
                acc[rr][1] += xv.x * w0.y + xv.y * w1.y + xv.z * w2.y + xv.w * w3.y;
                acc[rr][2] += xv.x * w0.z + xv.y * w1.z + xv.z * w2.z + xv.w * w3.z;
                acc[rr][3] += xv.x * w0.w + xv.y * w1.w + xv.z * w2.w + xv.w * w3.w;
            }
        }
        float4 bv = *(const float4*)(bo1 + tj * 4);
        float4 wv = *(const float4*)(Wo2 + tj * 4);
        #pragma unroll
        for (int rr = 0; rr < 2; ++rr) {
            float c = lrelu(acc[rr][0] + bv.x) * wv.x
                    + lrelu(acc[rr][1] + bv.y) * wv.y
                    + lrelu(acc[rr][2] + bv.z) * wv.z
                    + lrelu(acc[rr][3] + bv.w) * wv.w;
            #pragma unroll
            for (int off = 1; off < 64; off <<= 1) c += __shfl_xor(c, off);
            if (tj == 0) out[row0 + tr * 2 + rr] = c + bo2[0];
        }
    }
}

extern "C" void kernel_launch(void* const* d_in, const int* in_sizes, int n_in,
                              void* d_out, int out_size, void* d_ws, size_t ws_size,
                              hipStream_t stream) {
    const float* W_pi1 = (const float*)d_in[0];
    const float* b_pi1 = (const float*)d_in[1];
    const float* W_pi2 = (const float*)d_in[2];
    const float* b_pi2 = (const float*)d_in[3];
    const float* W_p1  = (const float*)d_in[8];
    const float* b_p1  = (const float*)d_in[9];
    const float* W_p2  = (const float*)d_in[10];
    const float* W_n1  = (const float*)d_in[12];
    const float* b_n1  = (const float*)d_in[13];
    const float* W_n2  = (const float*)d_in[14];
    const float* b_n2  = (const float*)d_in[15];
    const float* W_g1  = (const float*)d_in[16];
    const float* b_g1  = (const float*)d_in[17];
    const float* W_g2  = (const float*)d_in[18];
    const float* b_g2  = (const float*)d_in[19];
    const float* W_o1  = (const float*)d_in[20];
    const float* b_o1  = (const float*)d_in[21];
    const float* W_o2  = (const float*)d_in[22];
    const float* b_o2  = (const float*)d_in[23];
    const float* av    = (const float*)d_in[24];
    const float* delay = (const float*)d_in[26];
    const float* bit_pos = (const float*)d_in[27];
    const float* po_feat = (const float*)d_in[28];
    const int*   is_po   = (const int*)d_in[29];
    const int*   nbr_idx = (const int*)d_in[30];

    u16*   h_all = (u16*)d_ws;                                // NN*NH bf16 (33.5 MB)
    float* g_all = (float*)(h_all + (size_t)NN * NH);         // NN floats
    float* neigh = g_all + NN;                                // NM*NH floats
    float* cst   = neigh + (size_t)NM * NH;                   // 64 floats
    float* out   = (float*)d_out;

    precomp_kernel<<<1, 32, 0, stream>>>(W_p2, av, cst);

    level0_kernel<<<NM / 32, 512, 0, stream>>>(delay, W_pi1, b_pi1, W_pi2, b_pi2,
                                               av, h_all, g_all);

    for (int level = 1; level < NL; ++level) {
        attn_kernel<<<NM / 4, 256, 0, stream>>>(h_all, g_all, bit_pos, nbr_idx,
                                                W_p1, b_p1, cst, neigh, level);
        mlp_n_kernel<<<NM / 16, 256, 0, stream>>>(neigh, W_n1, b_n1, W_n2, b_n2,
                                                  is_po, av, h_all, g_all, level);
    }

    final_kernel<<<NM / 16, 512, 0, stream>>>(h_all + (size_t)(NN - NM) * NH, po_feat,
                                              W_g1, b_g1, W_g2, b_g2,
                                              W_o1, b_o1, W_o2, b_o2, out);
}

// Round 7
// 352.178 us; speedup vs baseline: 3.0110x; 1.1174x over previous
//
#include <hip/hip_runtime.h>

#define NL 8
#define NM 8192
#define ND 16
#define NH 256
#define NF 64
#define NN (NL * NM)

typedef unsigned short u16;

__device__ __forceinline__ float lrelu(float x) { return fmaxf(x, 0.1f * x); }

// f32 -> bf16 round-to-nearest-even
__device__ __forceinline__ u16 f2bf(float x) {
    union { float f; unsigned int u; } v; v.f = x;
    unsigned int r = (v.u + 0x7FFFu + ((v.u >> 16) & 1u)) >> 16;
    return (u16)r;
}
__device__ __forceinline__ ushort4 f4_to_bf4(float4 o) {
    ushort4 r; r.x = f2bf(o.x); r.y = f2bf(o.y); r.z = f2bf(o.z); r.w = f2bf(o.w);
    return r;
}
// unpack 2 bf16 packed in a u32 -> 2 floats (low half = first element)
__device__ __forceinline__ float2 bfp(unsigned int u) {
    union { unsigned int u; float f; } lo, hi;
    lo.u = u << 16; hi.u = u & 0xFFFF0000u;
    return make_float2(lo.f, hi.f);
}

// ---------- precompute attention constants: cst[32..63] = W_p2 @ av_p ----------
__global__ void precomp_kernel(const float* __restrict__ W_p2, const float* __restrict__ av,
                               float* __restrict__ cst)
{
    int j = threadIdx.x;   // 32 threads
    float w = 0.f;
    for (int k = 0; k < 32; ++k) w += W_p2[j * 32 + k] * av[32 + k];
    cst[32 + j] = w;
}

// ---------- Level 0: h = mlp_pi(delay) (bf16 store) + g epilogue ----------
__global__ __launch_bounds__(512) void level0_kernel(
    const float* __restrict__ delay,
    const float* __restrict__ W1, const float* __restrict__ b1,
    const float* __restrict__ W2, const float* __restrict__ b2,
    const float* __restrict__ av,
    u16* __restrict__ h_all, float* __restrict__ g_all)
{
    const int tid = threadIdx.x;
    const int row0 = blockIdx.x * 32;
    __shared__ __align__(16) float sH[32][128];

    for (int x = tid; x < 32 * 128; x += 512) {
        int r = x >> 7, j = x & 127;
        sH[r][j] = lrelu(delay[row0 + r] * W1[j] + b1[j]);
    }
    __syncthreads();

    const int tj = tid & 63, tr = tid >> 6;
    const float4 av4 = *(const float4*)(av + 64 + tj * 4);
    float acc[4][4];
    #pragma unroll
    for (int a = 0; a < 4; ++a)
        #pragma unroll
        for (int b = 0; b < 4; ++b) acc[a][b] = 0.f;

    for (int k = 0; k < 128; k += 4) {
        float4 w0 = *(const float4*)(W2 + (size_t)(k + 0) * 256 + tj * 4);
        float4 w1 = *(const float4*)(W2 + (size_t)(k + 1) * 256 + tj * 4);
        float4 w2 = *(const float4*)(W2 + (size_t)(k + 2) * 256 + tj * 4);
        float4 w3 = *(const float4*)(W2 + (size_t)(k + 3) * 256 + tj * 4);
        #pragma unroll
        for (int rr = 0; rr < 4; ++rr) {
            float4 xv = *(const float4*)(&sH[tr * 4 + rr][k]);
            acc[rr][0] += xv.x * w0.x + xv.y * w1.x + xv.z * w2.x + xv.w * w3.x;
            acc[rr][1] += xv.x * w0.y + xv.y * w1.y + xv.z * w2.y + xv.w * w3.y;
            acc[rr][2] += xv.x * w0.z + xv.y * w1.z + xv.z * w2.z + xv.w * w3.z;
            acc[rr][3] += xv.x * w0.w + xv.y * w1.w + xv.z * w2.w + xv.w * w3.w;
        }
    }
    float4 bv = *(const float4*)(b2 + tj * 4);
    #pragma unroll
    for (int rr = 0; rr < 4; ++rr) {
        const int row = row0 + tr * 4 + rr;
        float4 o;
        o.x = acc[rr][0] + bv.x; o.y = acc[rr][1] + bv.y;
        o.z = acc[rr][2] + bv.z; o.w = acc[rr][3] + bv.w;
        *(ushort4*)(h_all + (size_t)row * NH + tj * 4) = f4_to_bf4(o);
        float gp = o.x * av4.x + o.y * av4.y + o.z * av4.z + o.w * av4.w;
        #pragma unroll
        for (int off = 1; off < 64; off <<= 1) gp += __shfl_xor(gp, off);
        if (tj == 0) g_all[row] = gp;
    }
}

// ---------- Attention: 1 wave per m; g-gather alpha + single 16B-load streamed pass ----------
__global__ __launch_bounds__(256) void attn_kernel(
    const u16* __restrict__ h_all, const float* __restrict__ g_all,
    const float* __restrict__ bit_pos, const int* __restrict__ nbr_idx,
    const float* __restrict__ W_p1, const float* __restrict__ b_p1,
    const float* __restrict__ cst,
    float* __restrict__ neigh, int level)
{
    const int w = threadIdx.x >> 6, lane = threadIdx.x & 63;
    const int m = blockIdx.x * 4 + w;
    const int d = lane & 15, jj = lane >> 4;
    const size_t ebase = ((size_t)(level - 1) * NM + m) * ND;

    const int   idx = nbr_idx[ebase + d];
    const float bp  = bit_pos[ebase + d];

    // collapsed mlp_p: 4 jj-groups each cover 8 of the 32 hidden units
    float ep = 0.f;
    #pragma unroll
    for (int t = 0; t < 8; ++t) {
        int j = jj * 8 + t;
        ep += cst[32 + j] * lrelu(bp * W_p1[j] + b_p1[j]);
    }
    ep += __shfl_xor(ep, 16);
    ep += __shfl_xor(ep, 32);

    // e = e_h + e_p  (e_t is constant over d -> cancels in softmax)
    float e = g_all[idx] + ep;
    float mx = e;
    #pragma unroll
    for (int off = 1; off < 16; off <<= 1) mx = fmaxf(mx, __shfl_xor(mx, off));
    float wexp = __expf(e - mx);
    float s = wexp;
    #pragma unroll
    for (int off = 1; off < 16; off <<= 1) s += __shfl_xor(s, off);
    const float alpha = wexp / s;

    // streamed weighted sum: lane = rh*32 + cl; 16B (8 bf16) per lane, 2 rows/step
    const int rh = lane >> 5, cl = lane & 31;
    float4 a0 = make_float4(0.f, 0.f, 0.f, 0.f);
    float4 a1 = make_float4(0.f, 0.f, 0.f, 0.f);
    #pragma unroll
    for (int t = 0; t < 8; ++t) {
        const int d2 = t * 2 + rh;
        float a = __shfl(alpha, d2);
        int   r = __shfl(idx, d2);
        uint4 hv = *(const uint4*)(h_all + (size_t)r * NH + cl * 8);
        float2 p0 = bfp(hv.x), p1 = bfp(hv.y), p2 = bfp(hv.z), p3 = bfp(hv.w);
        a0.x += a * p0.x; a0.y += a * p0.y; a0.z += a * p1.x; a0.w += a * p1.y;
        a1.x += a * p2.x; a1.y += a * p2.y; a1.z += a * p3.x; a1.w += a * p3.y;
    }
    // combine the two row-halves
    a0.x += __shfl_xor(a0.x, 32); a0.y += __shfl_xor(a0.y, 32);
    a0.z += __shfl_xor(a0.z, 32); a0.w += __shfl_xor(a0.w, 32);
    a1.x += __shfl_xor(a1.x, 32); a1.y += __shfl_xor(a1.y, 32);
    a1.z += __shfl_xor(a1.z, 32); a1.w += __shfl_xor(a1.w, 32);

    float4 outv = (rh == 0) ? a0 : a1;
    *(float4*)(neigh + (size_t)m * NH + cl * 8 + rh * 4) = outv;
}

// ---------- Neighborhood MLP: 256 thr / 16 rows; col-split waves (weights read once/block) ----------
__global__ __launch_bounds__(256) void mlp_n_kernel(
    const float* __restrict__ neigh,
    const float* __restrict__ W1, const float* __restrict__ b1,
    const float* __restrict__ W2, const float* __restrict__ b2,
    const int* __restrict__ is_po, const float* __restrict__ av,
    u16* __restrict__ h_all, float* __restrict__ g_all, int level)
{
    const int tid = threadIdx.x;
    const int w = tid >> 6, lane = tid & 63;
    const int row0 = blockIdx.x * 16;
    __shared__ __align__(16) float sX[16][NH];
    __shared__ __align__(16) float sH[16][128];
    __shared__ float gpart[4][16];

    for (int x = tid; x < 16 * 64; x += 256) {
        int r = x >> 6, c = x & 63;
        *(float4*)(&sX[r][c * 4]) = *(const float4*)(neigh + (size_t)(row0 + r) * NH + c * 4);
    }
    __syncthreads();

    // layer 1: (16x256)@(256x128); wave w -> cols [w*32, w*32+32)
    {
        const int tj = lane & 7, tr = lane >> 3;   // 8 col-thr x 4 cols; 8 grp x 2 rows
        const int c0 = w * 32 + tj * 4;
        float acc[2][4];
        #pragma unroll
        for (int a = 0; a < 2; ++a)
            #pragma unroll
            for (int b = 0; b < 4; ++b) acc[a][b] = 0.f;

        for (int k = 0; k < NH; k += 4) {
            float4 w0 = *(const float4*)(W1 + (size_t)(k + 0) * 128 + c0);
            float4 w1 = *(const float4*)(W1 + (size_t)(k + 1) * 128 + c0);
            float4 w2 = *(const float4*)(W1 + (size_t)(k + 2) * 128 + c0);
            float4 w3 = *(const float4*)(W1 + (size_t)(k + 3) * 128 + c0);
            #pragma unroll
            for (int rr = 0; rr < 2; ++rr) {
                float4 xv = *(const float4*)(&sX[tr * 2 + rr][k]);
                acc[rr][0] += xv.x * w0.x + xv.y * w1.x + xv.z * w2.x + xv.w * w3.x;
                acc[rr][1] += xv.x * w0.y + xv.y * w1.y + xv.z * w2.y + xv.w * w3.y;
                acc[rr][2] += xv.x * w0.z + xv.y * w1.z + xv.z * w2.z + xv.w * w3.z;
                acc[rr][3] += xv.x * w0.w + xv.y * w1.w + xv.z * w2.w + xv.w * w3.w;
            }
        }
        float4 bv = *(const float4*)(b1 + c0);
        #pragma unroll
        for (int rr = 0; rr < 2; ++rr) {
            float4 o;
            o.x = lrelu(acc[rr][0] + bv.x); o.y = lrelu(acc[rr][1] + bv.y);
            o.z = lrelu(acc[rr][2] + bv.z); o.w = lrelu(acc[rr][3] + bv.w);
            *(float4*)(&sH[tr * 2 + rr][c0]) = o;
        }
    }
    __syncthreads();

    // layer 2: (16x128)@(128x256); wave w -> cols [w*64, w*64+64); cond-relu, bf16 store + g partial
    {
        const int tj = lane & 15, tr = lane >> 4;  // 16 col-thr x 4 cols; 4 grp x 4 rows
        const int c0 = w * 64 + tj * 4;
        const float4 av4 = *(const float4*)(av + 64 + c0);
        float acc[4][4];
        #pragma unroll
        for (int a = 0; a < 4; ++a)
            #pragma unroll
            for (int b = 0; b < 4; ++b) acc[a][b] = 0.f;

        for (int k = 0; k < 128; k += 4) {
            float4 w0 = *(const float4*)(W2 + (size_t)(k + 0) * 256 + c0);
            float4 w1 = *(const float4*)(W2 + (size_t)(k + 1) * 256 + c0);
            float4 w2 = *(const float4*)(W2 + (size_t)(k + 2) * 256 + c0);
            float4 w3 = *(const float4*)(W2 + (size_t)(k + 3) * 256 + c0);
            #pragma unroll
            for (int rr = 0; rr < 4; ++rr) {
                float4 xv = *(const float4*)(&sH[tr * 4 + rr][k]);
                acc[rr][0] += xv.x * w0.x + xv.y * w1.x + xv.z * w2.x + xv.w * w3.x;
                acc[rr][1] += xv.x * w0.y + xv.y * w1.y + xv.z * w2.y + xv.w * w3.y;
                acc[rr][2] += xv.x * w0.z + xv.y * w1.z + xv.z * w2.z + xv.w * w3.z;
                acc[rr][3] += xv.x * w0.w + xv.y * w1.w + xv.z * w2.w + xv.w * w3.w;
            }
        }
        float4 bv = *(const float4*)(b2 + c0);
        #pragma unroll
        for (int rr = 0; rr < 4; ++rr) {
            const int gm = level * NM + row0 + tr * 4 + rr;
            bool po = (is_po[gm] == 1);
            float4 o;
            o.x = acc[rr][0] + bv.x; o.y = acc[rr][1] + bv.y;
            o.z = acc[rr][2] + bv.z; o.w = acc[rr][3] + bv.w;
            if (!po) {
                o.x = fmaxf(o.x, 0.f); o.y = fmaxf(o.y, 0.f);
                o.z = fmaxf(o.z, 0.f); o.w = fmaxf(o.w, 0.f);
            }
            *(ushort4*)(h_all + (size_t)gm * NH + c0) = f4_to_bf4(o);
            float gp = o.x * av4.x + o.y * av4.y + o.z * av4.z + o.w * av4.w;
            gp += __shfl_xor(gp, 1); gp += __shfl_xor(gp, 2);
            gp += __shfl_xor(gp, 4); gp += __shfl_xor(gp, 8);
            if (tj == 0) gpart[w][tr * 4 + rr] = gp;
        }
    }
    __syncthreads();
    if (tid < 16)
        g_all[level * NM + row0 + tid] =
            gpart[0][tid] + gpart[1][tid] + gpart[2][tid] + gpart[3][tid];
}

// ---------- Final readout: 256 thr / 16 rows; col-split waves ----------
__global__ __launch_bounds__(256) void final_kernel(
    const u16* __restrict__ h_gnn, const float* __restrict__ po_feat,
    const float* __restrict__ Wg1, const float* __restrict__ bg1,
    const float* __restrict__ Wg2, const float* __restrict__ bg2,
    const float* __restrict__ Wo1, const float* __restrict__ bo1,
    const float* __restrict__ Wo2, const float* __restrict__ bo2,
    float* __restrict__ out)
{
    const int tid = threadIdx.x;
    const int w = tid >> 6, lane = tid & 63;
    const int row0 = blockIdx.x * 16;
    __shared__ __align__(16) float sx[16][512];
    __shared__ __align__(16) float sg[16][128];
    __shared__ float part[4][16];

    for (int x = tid; x < 16 * 32; x += 256) {
        int r = x >> 5, c = x & 31;
        uint4 hv = *(const uint4*)(h_gnn + (size_t)(row0 + r) * NH + c * 8);
        float2 p0 = bfp(hv.x), p1 = bfp(hv.y), p2 = bfp(hv.z), p3 = bfp(hv.w);
        float* dst = &sx[r][c * 8];
        dst[0] = p0.x; dst[1] = p0.y; dst[2] = p1.x; dst[3] = p1.y;
        dst[4] = p2.x; dst[5] = p2.y; dst[6] = p3.x; dst[7] = p3.y;
    }
    for (int x = tid; x < 16 * 128; x += 256) {
        int r = x >> 7, j = x & 127;
        sg[r][j] = lrelu(po_feat[row0 + r] * Wg1[j] + bg1[j]);
    }
    __syncthreads();

    // h_global = sg @ Wg2 + bg2 -> sx[:, 256:]; wave w -> cols [w*64, w*64+64)
    {
        const int tj = lane & 15, tr = lane >> 4;
        const int c0 = w * 64 + tj * 4;
        float acc[4][4];
        #pragma unroll
        for (int a = 0; a < 4; ++a)
            #pragma unroll
            for (int b = 0; b < 4; ++b) acc[a][b] = 0.f;

        for (int k = 0; k < 128; k += 4) {
            float4 w0 = *(const float4*)(Wg2 + (size_t)(k + 0) * 256 + c0);
            float4 w1 = *(const float4*)(Wg2 + (size_t)(k + 1) * 256 + c0);
            float4 w2 = *(const float4*)(Wg2 + (size_t)(k + 2) * 256 + c0);
            float4 w3 = *(const float4*)(Wg2 + (size_t)(k + 3) * 256 + c0);
            #pragma unroll
            for (int rr = 0; rr < 4; ++rr) {
                float4 xv = *(const float4*)(&sg[tr * 4 + rr][k]);
                acc[rr][0] += xv.x * w0.x + xv.y * w1.x + xv.z * w2.x + xv.w * w3.x;
                acc[rr][1] += xv.x * w0.y + xv.y * w1.y + xv.z * w2.y + xv.w * w3.y;
                acc[rr][2] += xv.x * w0.z + xv.y * w1.z + xv.z * w2.z + xv.w * w3.z;
                acc[rr][3] += xv.x * w0.w + xv.y * w1.w + xv.z * w2.w + xv.w * w3.w;
            }
        }
        float4 bv = *(const float4*)(bg2 + c0);
        #pragma unroll
        for (int rr = 0; rr < 4; ++rr) {
            float4 o;
            o.x = acc[rr][0] + bv.x; o.y = acc[rr][1] + bv.y;
            o.z = acc[rr][2] + bv.z; o.w = acc[rr][3] + bv.w;
            *(float4*)(&sx[tr * 4 + rr][256 + c0]) = o;
        }
    }
    __syncthreads();

    // o1 = lrelu(sx @ Wo1 + bo1), K=512, col-split; fused partial dot with Wo2
    {
        const int tj = lane & 15, tr = lane >> 4;
        const int c0 = w * 64 + tj * 4;
        float acc[4][4];
        #pragma unroll
        for (int a = 0; a < 4; ++a)
            #pragma unroll
            for (int b = 0; b < 4; ++b) acc[a][b] = 0.f;

        for (int k = 0; k < 512; k += 4) {
            float4 w0 = *(const float4*)(Wo1 + (size_t)(k + 0) * 256 + c0);
            float4 w1 = *(const float4*)(Wo1 + (size_t)(k + 1) * 256 + c0);
            float4 w2 = *(const float4*)(Wo1 + (size_t)(k + 2) * 256 + c0);
            float4 w3 = *(const float4*)(Wo1 + (size_t)(k + 3) * 256 + c0);
            #pragma unroll
            for (int rr = 0; rr < 4; ++rr) {
                float4 xv = *(const float4*)(&sx[tr * 4 + rr][k]);
                acc[rr][0] += xv.x * w0.x + xv.y * w1.x + xv.z * w2.x + xv.w * w3.x;
                acc[rr][1] += xv.x * w0.y + xv.y * w1.y + xv.z * w2.y + xv.w * w3.y;
                acc[rr][2] += xv.x * w0.z + xv.y * w1.z + xv.z * w2.z + xv.w * w3.z;
                acc[rr][3] += xv.x * w0.w + xv.y * w1.w + xv.z * w2.w + xv.w * w3.w;
            }
        }
        float4 bv = *(const float4*)(bo1 + c0);
        float4 wv = *(const float4*)(Wo2 + c0);
        #pragma unroll
        for (int rr = 0; rr < 4; ++rr) {
            float pc = lrelu(acc[rr][0] + bv.x) * wv.x
                     + lrelu(acc[rr][1] + bv.y) * wv.y
                     + lrelu(acc[rr][2] + bv.z) * wv.z
                     + lrelu(acc[rr][3] + bv.w) * wv.w;
            pc += __shfl_xor(pc, 1); pc += __shfl_xor(pc, 2);
            pc += __shfl_xor(pc, 4); pc += __shfl_xor(pc, 8);
            if (tj == 0) part[w][tr * 4 + rr] = pc;
        }
    }
    __syncthreads();
    if (tid < 16)
        out[row0 + tid] = part[0][tid] + part[1][tid] + part[2][tid] + part[3][tid] + bo2[0];
}

extern "C" void kernel_launch(void* const* d_in, const int* in_sizes, int n_in,
                              void* d_out, int out_size, void* d_ws, size_t ws_size,
                              hipStream_t stream) {
    const float* W_pi1 = (const float*)d_in[0];
    const float* b_pi1 = (const float*)d_in[1];
    const float* W_pi2 = (const float*)d_in[2];
    const float* b_pi2 = (const float*)d_in[3];
    const float* W_p1  = (const float*)d_in[8];
    const float* b_p1  = (const float*)d_in[9];
    const float* W_p2  = (const float*)d_in[10];
    const float* W_n1  = (const float*)d_in[12];
    const float* b_n1  = (const float*)d_in[13];
    const float* W_n2  = (const float*)d_in[14];
    const float* b_n2  = (const float*)d_in[15];
    const float* W_g1  = (const float*)d_in[16];
    const float* b_g1  = (const float*)d_in[17];
    const float* W_g2  = (const float*)d_in[18];
    const float* b_g2  = (const float*)d_in[19];
    const float* W_o1  = (const float*)d_in[20];
    const float* b_o1  = (const float*)d_in[21];
    const float* W_o2  = (const float*)d_in[22];
    const float* b_o2  = (const float*)d_in[23];
    const float* av    = (const float*)d_in[24];
    const float* delay = (const float*)d_in[26];
    const float* bit_pos = (const float*)d_in[27];
    const float* po_feat = (const float*)d_in[28];
    const int*   is_po   = (const int*)d_in[29];
    const int*   nbr_idx = (const int*)d_in[30];

    u16*   h_all = (u16*)d_ws;                                // NN*NH bf16 (33.5 MB)
    float* g_all = (float*)(h_all + (size_t)NN * NH);         // NN floats
    float* neigh = g_all + NN;                                // NM*NH floats
    float* cst   = neigh + (size_t)NM * NH;                   // 64 floats
    float* out   = (float*)d_out;

    precomp_kernel<<<1, 32, 0, stream>>>(W_p2, av, cst);

    level0_kernel<<<NM / 32, 512, 0, stream>>>(delay, W_pi1, b_pi1, W_pi2, b_pi2,
                                               av, h_all, g_all);

    for (int level = 1; level < NL; ++level) {
        attn_kernel<<<NM / 4, 256, 0, stream>>>(h_all, g_all, bit_pos, nbr_idx,
                                                W_p1, b_p1, cst, neigh, level);
        mlp_n_kernel<<<NM / 16, 256, 0, stream>>>(neigh, W_n1, b_n1, W_n2, b_n2,
                                                  is_po, av, h_all, g_all, level);
    }

    final_kernel<<<NM / 16, 256, 0, stream>>>(h_all + (size_t)(NN - NM) * NH, po_feat,
                                              W_g1, b_g1, W_g2, b_g2,
                                              W_o1, b_o1, W_o2, b_o2, out);
}